// Round 15
// baseline (101.902 us; speedup 1.0000x reference)
//
#include <hip/hip_runtime.h>
#include <hip/hip_bf16.h>

#define T_TOK 2048
#define D_    512
#define TWO_D 1024
#define M_    64

typedef float  f32x4  __attribute__((ext_vector_type(4)));
typedef __bf16 bf16x8 __attribute__((ext_vector_type(8)));
typedef unsigned short ushort8v __attribute__((ext_vector_type(8)));

__device__ __forceinline__ ushort f2bf(float f) {
    union { __hip_bfloat16 h; ushort u; } cv;
    cv.h = __float2bfloat16(f);
    return cv.u;
}
__device__ __forceinline__ float bf2f(ushort u) {
    union { unsigned int i; float f; } c; c.i = ((unsigned int)u) << 16; return c.f;
}

// async global->LDS, 16 bytes per lane (dest linear: uniform base + lane*16)
__device__ __forceinline__ void gl16(const void* g, void* l) {
    __builtin_amdgcn_global_load_lds(
        (const __attribute__((address_space(1))) unsigned int*)g,
        (__attribute__((address_space(3))) unsigned int*)l, 16, 0, 0);
}

// ---------------- prep: cast x -> xs[:,0:512] bf16  AND  split ctx hi/lo -----
__global__ __launch_bounds__(256) void k_prep(const float* __restrict__ x,
                                              const float* __restrict__ ctx,
                                              ushort* __restrict__ xs,
                                              ushort* __restrict__ cH,
                                              ushort* __restrict__ cL) {
    int b = blockIdx.x;
    int idx = (b & 1023) * 256 + threadIdx.x;
    if (b < 1024) {
        int e4  = idx * 4;
        int t   = e4 >> 9;
        int d   = e4 & 511;
        float4 v = *reinterpret_cast<const float4*>(x + e4);
        ushort4 o;
        o.x = f2bf(v.x); o.y = f2bf(v.y); o.z = f2bf(v.z); o.w = f2bf(v.w);
        *reinterpret_cast<ushort4*>(xs + (size_t)t * TWO_D + d) = o;
    } else {
        float4 v = *reinterpret_cast<const float4*>(ctx + (size_t)idx * 4);
        ushort4 h, l;
        h.x = f2bf(v.x); l.x = f2bf(v.x - bf2f(h.x));
        h.y = f2bf(v.y); l.y = f2bf(v.y - bf2f(h.y));
        h.z = f2bf(v.z); l.z = f2bf(v.z - bf2f(h.z));
        h.w = f2bf(v.w); l.w = f2bf(v.w - bf2f(h.w));
        *reinterpret_cast<ushort4*>(cH + (size_t)idx * 4) = h;
        *reinterpret_cast<ushort4*>(cL + (size_t)idx * 4) = l;
    }
}

// ---------------- split + transpose W1 [512][1024] -> W1T hi/lo [1024][512] --
__global__ __launch_bounds__(256) void k_split_w1t(const float* __restrict__ W1,
                                                   ushort* __restrict__ w1th,
                                                   ushort* __restrict__ w1tl) {
    int t  = threadIdx.x;
    int n  = blockIdx.x * 64 + (t >> 2);
    int kb = blockIdx.y * 64 + (t & 3) * 16;
#pragma unroll
    for (int j = 0; j < 16; j += 4) {
        ushort hh[4], ll[4];
#pragma unroll
        for (int i = 0; i < 4; i++) {
            float v = W1[(size_t)(kb + j + i) * TWO_D + n];
            ushort h = f2bf(v);
            hh[i] = h;
            ll[i] = f2bf(v - bf2f(h));
        }
        ushort4 h4, l4;
        h4.x = hh[0]; h4.y = hh[1]; h4.z = hh[2]; h4.w = hh[3];
        l4.x = ll[0]; l4.y = ll[1]; l4.z = ll[2]; l4.w = ll[3];
        *reinterpret_cast<ushort4*>(&w1th[(size_t)n * D_ + kb + j]) = h4;
        *reinterpret_cast<ushort4*>(&w1tl[(size_t)n * D_ + kb + j]) = l4;
    }
}

// ---------------- cast + transpose Wi [1024][512] -> wiT bf16 [512][1024] ----
__global__ __launch_bounds__(256) void k_prep_wi(const float* __restrict__ Wi,
                                                 ushort* __restrict__ wiT) {
    int t  = threadIdx.x;
    int n  = blockIdx.x * 64 + (t >> 2);     // n in [0,512)
    int kb = blockIdx.y * 64 + (t & 3) * 16; // k in [0,1024)
#pragma unroll
    for (int j = 0; j < 16; j += 4) {
        ushort hh[4];
#pragma unroll
        for (int i = 0; i < 4; i++)
            hh[i] = f2bf(Wi[(size_t)(kb + j + i) * D_ + n]);
        ushort4 h4;
        h4.x = hh[0]; h4.y = hh[1]; h4.z = hh[2]; h4.w = hh[3];
        *reinterpret_cast<ushort4*>(&wiT[(size_t)n * TWO_D + kb + j]) = h4;
    }
}

// ---------------- selector GEMM1 via split-bf16 MFMA, BK=64 ------------------
__global__ __launch_bounds__(256) void k_gemm1s(const ushort* __restrict__ cH,
                                                const ushort* __restrict__ cL,
                                                const ushort* __restrict__ w1th,
                                                const ushort* __restrict__ w1tl,
                                                const float* __restrict__ b1,
                                                float* __restrict__ H) {
    int col0 = blockIdx.x * 64, r0 = blockIdx.y * 64;
    __shared__ ushort sAH[2 * 4096], sAL[2 * 4096];
    __shared__ ushort sBH[2 * 4096], sBL[2 * 4096];
    int t = threadIdx.x, lane = t & 63, wave = t >> 6;
    int wm = wave >> 1, wn = wave & 1;
    int lr = lane & 15, kq = lane >> 4;

    const ushort* srcAH = cH  + (size_t)(r0  + (t >> 3)) * D_ + (t & 7) * 8;
    const ushort* srcAL = cL  + (size_t)(r0  + (t >> 3)) * D_ + (t & 7) * 8;
    const ushort* srcBH = w1th + (size_t)(col0 + (t >> 3)) * D_ + (t & 7) * 8;
    const ushort* srcBL = w1tl + (size_t)(col0 + (t >> 3)) * D_ + (t & 7) * 8;
    int r2 = (256 + t) >> 3, p2 = ((256 + t) & 7) * 8;
    const ushort* srcAH2 = cH  + (size_t)(r0  + r2) * D_ + p2;
    const ushort* srcAL2 = cL  + (size_t)(r0  + r2) * D_ + p2;
    const ushort* srcBH2 = w1th + (size_t)(col0 + r2) * D_ + p2;
    const ushort* srcBL2 = w1tl + (size_t)(col0 + r2) * D_ + p2;

    f32x4 acc[2][2];
#pragma unroll
    for (int i = 0; i < 2; i++)
#pragma unroll
        for (int j = 0; j < 2; j++)
#pragma unroll
            for (int r = 0; r < 4; r++) acc[i][j][r] = 0.0f;

    gl16(srcAH, &sAH[0] + t * 8);  gl16(srcAH2, &sAH[0] + 2048 + t * 8);
    gl16(srcAL, &sAL[0] + t * 8);  gl16(srcAL2, &sAL[0] + 2048 + t * 8);
    gl16(srcBH, &sBH[0] + t * 8);  gl16(srcBH2, &sBH[0] + 2048 + t * 8);
    gl16(srcBL, &sBL[0] + t * 8);  gl16(srcBL2, &sBL[0] + 2048 + t * 8);
    __syncthreads();

    int cur = 0;
    for (int k0 = 0; k0 < D_; k0 += 64) {
        int nxt = cur ^ 1;
        if (k0 + 64 < D_) {
            int kn = k0 + 64;
            gl16(srcAH + kn, &sAH[nxt * 4096] + t * 8);  gl16(srcAH2 + kn, &sAH[nxt * 4096] + 2048 + t * 8);
            gl16(srcAL + kn, &sAL[nxt * 4096] + t * 8);  gl16(srcAL2 + kn, &sAL[nxt * 4096] + 2048 + t * 8);
            gl16(srcBH + kn, &sBH[nxt * 4096] + t * 8);  gl16(srcBH2 + kn, &sBH[nxt * 4096] + 2048 + t * 8);
            gl16(srcBL + kn, &sBL[nxt * 4096] + t * 8);  gl16(srcBL2 + kn, &sBL[nxt * 4096] + 2048 + t * 8);
        }
#pragma unroll
        for (int kc = 0; kc < 2; kc++) {
            bf16x8 ah[2], al[2], bh[2], bl[2];
#pragma unroll
            for (int i = 0; i < 2; i++) {
                int off = cur * 4096 + (wm * 32 + i * 16 + lr) * 64 + kc * 32 + kq * 8;
                ah[i] = *reinterpret_cast<const bf16x8*>(&sAH[off]);
                al[i] = *reinterpret_cast<const bf16x8*>(&sAL[off]);
            }
#pragma unroll
            for (int j = 0; j < 2; j++) {
                int off = cur * 4096 + (wn * 32 + j * 16 + lr) * 64 + kc * 32 + kq * 8;
                bh[j] = *reinterpret_cast<const bf16x8*>(&sBH[off]);
                bl[j] = *reinterpret_cast<const bf16x8*>(&sBL[off]);
            }
#pragma unroll
            for (int i = 0; i < 2; i++)
#pragma unroll
                for (int j = 0; j < 2; j++) {
                    acc[i][j] = __builtin_amdgcn_mfma_f32_16x16x32_bf16(ah[i], bh[j], acc[i][j], 0, 0, 0);
                    acc[i][j] = __builtin_amdgcn_mfma_f32_16x16x32_bf16(ah[i], bl[j], acc[i][j], 0, 0, 0);
                    acc[i][j] = __builtin_amdgcn_mfma_f32_16x16x32_bf16(al[i], bh[j], acc[i][j], 0, 0, 0);
                }
        }
        __syncthreads();
        cur = nxt;
    }

#pragma unroll
    for (int i = 0; i < 2; i++)
#pragma unroll
        for (int j = 0; j < 2; j++) {
            int col = col0 + wn * 32 + j * 16 + lr;
            float bb = b1[col];
#pragma unroll
            for (int r = 0; r < 4; r++) {
                int row = r0 + wm * 32 + i * 16 + kq * 4 + r;
                float v = acc[i][j][r] + bb;
                H[(size_t)row * TWO_D + col] = 0.5f * v * (1.0f + erff(v * 0.70710678118654752f));
            }
        }
}

// ---------------- logits partials: fp32 GEMM, K split across blocks ----------
__global__ __launch_bounds__(256) void k_logits(const float* __restrict__ H,
                                                const float* __restrict__ x,
                                                const float* __restrict__ W2,
                                                const float* __restrict__ Wg,
                                                float* __restrict__ partial) {
    __shared__ float sa[64][36];
    __shared__ float sb[32][64];
    int tx = threadIdx.x & 15, ty = threadIdx.x >> 4;
    int cx = blockIdx.x;
    int row0 = blockIdx.y * 64;

    const float* Asrc; int lda, koff;
    if (cx < 8) { Asrc = H; lda = TWO_D; koff = cx * 128; }
    else        { Asrc = x; lda = D_;    koff = (cx - 8) * 128; }

    float acc[4][4];
#pragma unroll
    for (int i = 0; i < 4; i++)
#pragma unroll
        for (int j = 0; j < 4; j++) acc[i][j] = 0.0f;

    for (int k0 = 0; k0 < 128; k0 += 32) {
#pragma unroll
        for (int q = 0; q < 2; q++) {
            int f = threadIdx.x * 2 + q;
            int r = f >> 3, c = (f & 7) * 4;
            *reinterpret_cast<float4*>(&sa[r][c]) =
                *reinterpret_cast<const float4*>(&Asrc[(size_t)(row0 + r) * lda + koff + k0 + c]);
            if (cx < 8) {
                int kk = f >> 4, n4 = (f & 15) * 4;
                *reinterpret_cast<float4*>(&sb[kk][n4]) =
                    *reinterpret_cast<const float4*>(&W2[(size_t)(koff + k0 + kk) * M_ + n4]);
            } else {
                int m = f >> 3, kq = f & 7;
                float4 v2 = *reinterpret_cast<const float4*>(&Wg[(size_t)m * D_ + koff + k0 + kq * 4]);
                sb[kq * 4 + 0][m] = v2.x; sb[kq * 4 + 1][m] = v2.y;
                sb[kq * 4 + 2][m] = v2.z; sb[kq * 4 + 3][m] = v2.w;
            }
        }
        __syncthreads();
#pragma unroll
        for (int kk = 0; kk < 32; kk++) {
            float a0 = sa[ty * 4 + 0][kk], a1 = sa[ty * 4 + 1][kk];
            float a2 = sa[ty * 4 + 2][kk], a3 = sa[ty * 4 + 3][kk];
            float4 b4 = *reinterpret_cast<float4*>(&sb[kk][tx * 4]);
            acc[0][0] += a0 * b4.x; acc[0][1] += a0 * b4.y; acc[0][2] += a0 * b4.z; acc[0][3] += a0 * b4.w;
            acc[1][0] += a1 * b4.x; acc[1][1] += a1 * b4.y; acc[1][2] += a1 * b4.z; acc[1][3] += a1 * b4.w;
            acc[2][0] += a2 * b4.x; acc[2][1] += a2 * b4.y; acc[2][2] += a2 * b4.z; acc[2][3] += a2 * b4.w;
            acc[3][0] += a3 * b4.x; acc[3][1] += a3 * b4.y; acc[3][2] += a3 * b4.z; acc[3][3] += a3 * b4.w;
        }
        __syncthreads();
    }
#pragma unroll
    for (int i = 0; i < 4; i++) {
        int row = row0 + ty * 4 + i;
        float4 o;
        float* oc = reinterpret_cast<float*>(&o);
#pragma unroll
        for (int j = 0; j < 4; j++) oc[j] = acc[i][j];
        *reinterpret_cast<float4*>(&partial[((size_t)cx * T_TOK + row) * M_ + tx * 4]) = o;
    }
}

// ---------------- top-k: one token per wave; no atomics ----------------------
__global__ __launch_bounds__(256) void k_topk(const float* __restrict__ partial,
                                              const float* __restrict__ b2,
                                              const float* __restrict__ bg,
                                              int* __restrict__ tope,
                                              float* __restrict__ topw) {
    int t = threadIdx.x;
    int wave = t >> 6, lane = t & 63;
    int tok = blockIdx.x * 4 + wave;

    float l = b2[lane];
#pragma unroll
    for (int c = 0; c < 8; c++)
        l += partial[((size_t)c * T_TOK + tok) * M_ + lane];
    float g = bg[lane];
#pragma unroll
    for (int c = 8; c < 12; c++)
        g += partial[((size_t)c * T_TOK + tok) * M_ + lane];

    float mx = l;
#pragma unroll
    for (int off = 1; off < 64; off <<= 1) mx = fmaxf(mx, __shfl_xor(mx, off));
    float ev = expf(l - mx);
    float s = ev;
#pragma unroll
    for (int off = 1; off < 64; off <<= 1) s += __shfl_xor(s, off);
    float p = ev / s;

    float pm = p;
    int bi0, bi1, bi2, bi3; float bv0, bv1, bv2, bv3;
#pragma unroll
    for (int k = 0; k < 4; k++) {
        float bv = pm; int bi = lane;
#pragma unroll
        for (int off = 1; off < 64; off <<= 1) {
            float ov = __shfl_xor(bv, off);
            int   oi = __shfl_xor(bi, off);
            if (ov > bv || (ov == bv && oi < bi)) { bv = ov; bi = oi; }
        }
        if (k == 0) { bi0 = bi; bv0 = bv; }
        else if (k == 1) { bi1 = bi; bv1 = bv; }
        else if (k == 2) { bi2 = bi; bv2 = bv; }
        else { bi3 = bi; bv3 = bv; }
        if (lane == bi) pm = -1.0f;
    }
    float sum4 = bv0 + bv1 + bv2 + bv3;
    int   esel = (lane == 0) ? bi0 : (lane == 1) ? bi1 : (lane == 2) ? bi2 : bi3;
    float pv   = (lane == 0) ? bv0 : (lane == 1) ? bv1 : (lane == 2) ? bv2 : bv3;
    float gv = __shfl(g, esel);
    if (lane < 4) {
        float gate = 1.0f / (1.0f + expf(-gv));
        tope[tok * 4 + lane] = esel;
        topw[tok * 4 + lane] = (pv / sum4) * gate;
    }
}

// ---------------- bucket build: 1 block/expert, 4 waves, int4 scan ----------
__global__ __launch_bounds__(256) void k_bucket(const int* __restrict__ tope,
                                                const float* __restrict__ topw,
                                                int* __restrict__ counts,
                                                int* __restrict__ bslot,
                                                float* __restrict__ bw) {
    int e = blockIdx.x;
    int t = threadIdx.x, lane = t & 63, wave = t >> 6;
    __shared__ int s_wsum[4];
    __shared__ int s_base;
    if (t == 0) s_base = 0;

    for (int it = 0; it < 8; it++) {
        int base = it * 1024 + t * 4;
        int4 ev = *reinterpret_cast<const int4*>(tope + base);
        bool m0 = (ev.x == e), m1 = (ev.y == e), m2 = (ev.z == e), m3 = (ev.w == e);
        unsigned long long b0 = __ballot(m0), b1 = __ballot(m1);
        unsigned long long b2 = __ballot(m2), b3 = __ballot(m3);
        unsigned long long below = (lane == 0) ? 0ULL : ((~0ULL) >> (64 - lane));
        int pre_lane = __popcll(b0 & below) + __popcll(b1 & below)
                     + __popcll(b2 & below) + __popcll(b3 & below);
        int wtot = __popcll(b0) + __popcll(b1) + __popcll(b2) + __popcll(b3);
        if (lane == 0) s_wsum[wave] = wtot;
        __syncthreads();
        int wbase = s_base;
#pragma unroll
        for (int w = 0; w < 4; w++)
            if (w < wave) wbase += s_wsum[w];
        int pos = wbase + pre_lane;
        if (m0) { bslot[e * T_TOK + pos] = base + 0; bw[e * T_TOK + pos] = topw[base + 0]; pos++; }
        if (m1) { bslot[e * T_TOK + pos] = base + 1; bw[e * T_TOK + pos] = topw[base + 1]; pos++; }
        if (m2) { bslot[e * T_TOK + pos] = base + 2; bw[e * T_TOK + pos] = topw[base + 2]; pos++; }
        if (m3) { bslot[e * T_TOK + pos] = base + 3; bw[e * T_TOK + pos] = topw[base + 3]; pos++; }
        __syncthreads();
        if (t == 0) s_base += s_wsum[0] + s_wsum[1] + s_wsum[2] + s_wsum[3];
    }
    __syncthreads();
    if (t == 0) counts[e] = s_base;
}

// ---------------- build dense work-item list: sched[0]=NI, sched[1+i]=(e<<16)|ytile
__global__ __launch_bounds__(64) void k_items(const int* __restrict__ counts,
                                              int* __restrict__ sched) {
    int t = threadIdx.x;
    int cnt = counts[t];
    int nty = (cnt + 63) >> 6;
    int off = nty;
    for (int d = 1; d < 64; d <<= 1) {
        int v = __shfl_up(off, d);
        if (t >= d) off += v;
    }
    int base = off - nty;
    for (int y = 0; y < nty; y++)
        sched[1 + base + y] = (t << 16) | y;
    if (t == 63) sched[0] = off;
}

// ---------------- grouped expert GEMM (bf16 MFMA), BK=32, work-list grid ----
__global__ __launch_bounds__(256) void k_expert(const ushort* __restrict__ xs,
                                                const float* __restrict__ Wt,
                                                const float* __restrict__ bt,
                                                const float* __restrict__ ch,
                                                const int* __restrict__ counts,
                                                const int* __restrict__ bslot,
                                                const float* __restrict__ bw,
                                                const int* __restrict__ sched,
                                                ushort* __restrict__ scratch) {
    int yi = blockIdx.y;
    if (yi >= sched[0]) return;
    int item = sched[1 + yi];
    int e  = item >> 16;
    int y0 = (item & 0xffff) << 6;
    int cnt = counts[e];
    int n0 = blockIdx.x * 64;

    __shared__ ushort saF[2 * 64 * 32];
    __shared__ float  sbF[2 * 32 * 64];
    __shared__ int    s_slot[64];
    __shared__ float  s_w[64];

    int t = threadIdx.x;
    if (t < 64) {
        int i = y0 + t;
        if (i < cnt) { s_slot[t] = bslot[e * T_TOK + i]; s_w[t] = bw[e * T_TOK + i]; }
        else         { s_slot[t] = -1;                   s_w[t] = 0.0f; }
    }
    __syncthreads();

    int lane = t & 63, wave = t >> 6;
    int wm = wave >> 1, wn = wave & 1;
    int lr = lane & 15, kq = lane >> 4;

    int rA = t >> 2, qA = t & 3;
    int slotA = s_slot[rA];
    const ushort* srcA = xs + (size_t)((slotA >= 0) ? (slotA >> 2) : 0) * TWO_D + qA * 8;
    const float* srcB0 = &Wt[((size_t)e * D_ + (t >> 4)) * D_ + n0 + (t & 15) * 4];
    const float* srcB1 = &Wt[((size_t)e * D_ + 16 + (t >> 4)) * D_ + n0 + (t & 15) * 4];

    f32x4 acc[2][2];
#pragma unroll
    for (int i = 0; i < 2; i++)
#pragma unroll
        for (int j = 0; j < 2; j++)
#pragma unroll
            for (int r = 0; r < 4; r++) acc[i][j][r] = 0.0f;

    gl16(srcA, &saF[0] + t * 8);
    gl16(srcB0, &sbF[0] + t * 4);
    gl16(srcB1, &sbF[0] + 1024 + t * 4);
    __syncthreads();

    int cur = 0;
    for (int k0 = 0; k0 < D_; k0 += 32) {
        int nxt = cur ^ 1;
        if (k0 + 32 < D_) {
            gl16(srcA + k0 + 32, &saF[nxt * 2048] + t * 8);
            gl16(srcB0 + (size_t)(k0 + 32) * D_, &sbF[nxt * 2048] + t * 4);
            gl16(srcB1 + (size_t)(k0 + 32) * D_, &sbF[nxt * 2048] + 1024 + t * 4);
        }
        bf16x8 af[2], bfr[2];
#pragma unroll
        for (int i = 0; i < 2; i++)
            af[i] = *reinterpret_cast<const bf16x8*>(&saF[cur * 2048 + (wm * 32 + i * 16 + lr) * 32 + kq * 8]);
#pragma unroll
        for (int j = 0; j < 2; j++) {
            int col = wn * 32 + j * 16 + lr;
            union { ushort us[8]; bf16x8 v; } pk;
#pragma unroll
            for (int jj = 0; jj < 8; jj++)
                pk.us[jj] = f2bf(sbF[cur * 2048 + (kq * 8 + jj) * 64 + col]);
            bfr[j] = pk.v;
        }
#pragma unroll
        for (int i = 0; i < 2; i++)
#pragma unroll
            for (int j = 0; j < 2; j++)
                acc[i][j] = __builtin_amdgcn_mfma_f32_16x16x32_bf16(af[i], bfr[j], acc[i][j], 0, 0, 0);
        __syncthreads();
        cur = nxt;
    }

#pragma unroll
    for (int i = 0; i < 2; i++)
#pragma unroll
        for (int j = 0; j < 2; j++) {
            int col = n0 + wn * 32 + j * 16 + lr;
            float bias = bt[(size_t)e * D_ + col] + ch[(size_t)e * D_ + col];
#pragma unroll
            for (int r = 0; r < 4; r++) {
                int rl = wm * 32 + i * 16 + kq * 4 + r;
                int slot = s_slot[rl];
                if (slot >= 0)
                    scratch[(size_t)slot * D_ + col] = f2bf((acc[i][j][r] + bias) * s_w[rl]);
            }
        }
}

// ---------------- combine 4 slots -> selected (bf16) into xs[:, 512:] -------
__global__ __launch_bounds__(256) void k_combine(const ushort* __restrict__ scratch,
                                                 ushort* __restrict__ xs) {
    int tid = blockIdx.x * 256 + threadIdx.x;   // 512 blocks x 256
    int token = tid >> 6;
    int d8 = (tid & 63) * 8;
    float s[8];
#pragma unroll
    for (int j = 0; j < 8; j++) s[j] = 0.0f;
#pragma unroll
    for (int r = 0; r < 4; r++) {
        ushort8v v = *reinterpret_cast<const ushort8v*>(scratch + ((size_t)token * 4 + r) * D_ + d8);
#pragma unroll
        for (int j = 0; j < 8; j++) s[j] += bf2f(v[j]);
    }
    ushort8v o;
#pragma unroll
    for (int j = 0; j < 8; j++) o[j] = f2bf(s[j]);
    *reinterpret_cast<ushort8v*>(xs + (size_t)token * TWO_D + D_ + d8) = o;
}

// ---------------- integrate: out = [x, selected] @ wiT + int_b, BK=64 -------
// B pre-cast bf16 transposed -> contiguous gl16 staging + b128 fragment reads.
__global__ __launch_bounds__(256) void k_integrate(const ushort* __restrict__ xs,
                                                   const ushort* __restrict__ wiT,
                                                   const float* __restrict__ bi,
                                                   float* __restrict__ out) {
    int n0 = blockIdx.x * 64, r0 = blockIdx.y * 64;
    __shared__ ushort saF[2 * 4096];
    __shared__ ushort sbB[2 * 4096];
    int t = threadIdx.x, lane = t & 63, wave = t >> 6;
    int wm = wave >> 1, wn = wave & 1;
    int lr = lane & 15, kq = lane >> 4;

    int rA0 = t >> 3, pA0 = (t & 7) * 8;
    int rA1 = (256 + t) >> 3, pA1 = ((256 + t) & 7) * 8;
    const ushort* srcA0 = xs + (size_t)(r0 + rA0) * TWO_D + pA0;
    const ushort* srcA1 = xs + (size_t)(r0 + rA1) * TWO_D + pA1;
    const ushort* srcB0 = wiT + (size_t)(n0 + rA0) * TWO_D + pA0;
    const ushort* srcB1 = wiT + (size_t)(n0 + rA1) * TWO_D + pA1;

    f32x4 acc[2][2];
#pragma unroll
    for (int i = 0; i < 2; i++)
#pragma unroll
        for (int j = 0; j < 2; j++)
#pragma unroll
            for (int r = 0; r < 4; r++) acc[i][j][r] = 0.0f;

    gl16(srcA0, &saF[0] + t * 8);
    gl16(srcA1, &saF[0] + 2048 + t * 8);
    gl16(srcB0, &sbB[0] + t * 8);
    gl16(srcB1, &sbB[0] + 2048 + t * 8);
    __syncthreads();

    int cur = 0;
    for (int k0 = 0; k0 < TWO_D; k0 += 64) {
        int nxt = cur ^ 1;
        if (k0 + 64 < TWO_D) {
            int kn = k0 + 64;
            gl16(srcA0 + kn, &saF[nxt * 4096] + t * 8);
            gl16(srcA1 + kn, &saF[nxt * 4096] + 2048 + t * 8);
            gl16(srcB0 + kn, &sbB[nxt * 4096] + t * 8);
            gl16(srcB1 + kn, &sbB[nxt * 4096] + 2048 + t * 8);
        }
#pragma unroll
        for (int kc = 0; kc < 2; kc++) {
            bf16x8 af[2], bfr[2];
#pragma unroll
            for (int i = 0; i < 2; i++)
                af[i] = *reinterpret_cast<const bf16x8*>(
                    &saF[cur * 4096 + (wm * 32 + i * 16 + lr) * 64 + kc * 32 + kq * 8]);
#pragma unroll
            for (int j = 0; j < 2; j++)
                bfr[j] = *reinterpret_cast<const bf16x8*>(
                    &sbB[cur * 4096 + (wn * 32 + j * 16 + lr) * 64 + kc * 32 + kq * 8]);
#pragma unroll
            for (int i = 0; i < 2; i++)
#pragma unroll
                for (int j = 0; j < 2; j++)
                    acc[i][j] = __builtin_amdgcn_mfma_f32_16x16x32_bf16(af[i], bfr[j], acc[i][j], 0, 0, 0);
        }
        __syncthreads();
        cur = nxt;
    }

#pragma unroll
    for (int i = 0; i < 2; i++)
#pragma unroll
        for (int j = 0; j < 2; j++) {
            int col = n0 + wn * 32 + j * 16 + lr;
            float bb = bi[col];
#pragma unroll
            for (int r = 0; r < 4; r++) {
                int row = r0 + wm * 32 + i * 16 + kq * 4 + r;
                out[(size_t)row * D_ + col] = acc[i][j][r] + bb;
            }
        }
}

extern "C" void kernel_launch(void* const* d_in, const int* in_sizes, int n_in,
                              void* d_out, int out_size, void* d_ws, size_t ws_size,
                              hipStream_t stream) {
    const float* x   = (const float*)d_in[0];
    const float* ctx = (const float*)d_in[1];
    const float* Wt  = (const float*)d_in[2];
    const float* bt  = (const float*)d_in[3];
    const float* ch  = (const float*)d_in[4];
    const float* Wg  = (const float*)d_in[5];
    const float* bg  = (const float*)d_in[6];
    const float* W1  = (const float*)d_in[7];
    const float* b1  = (const float*)d_in[8];
    const float* W2  = (const float*)d_in[9];
    const float* b2  = (const float*)d_in[10];
    const float* Wi  = (const float*)d_in[11];
    const float* bi  = (const float*)d_in[12];
    float* out = (float*)d_out;

    char* ws = (char*)d_ws;
    float*  H       = (float*)(ws + 0);                 //  8 MB
    ushort* xs      = (ushort*)(ws + 8388608);          //  4 MB
    int*    counts  = (int*)(ws + 12582912);            //  1 KB
    int*    bslot   = (int*)(ws + 12583936);            // 512 KB
    float*  bw      = (float*)(ws + 13108224);          // 512 KB
    ushort* scratch = (ushort*)(ws + 13632512);         //  8 MB [8192][512] bf16
    float*  partial = (float*)(ws + 22021120);          //  6 MB [12][2048][64]
    ushort* ctxH    = (ushort*)(ws + 28312576);         //  2 MB
    ushort* ctxL    = (ushort*)(ws + 30409728);         //  2 MB
    ushort* w1th    = (ushort*)(ws + 32506880);         //  1 MB
    ushort* w1tl    = (ushort*)(ws + 33555456);         //  1 MB
    ushort* wiT     = (ushort*)(ws + 34604032);         //  1 MB [512][1024] bf16
    int*    sched   = (int*)(ws + 35652608);            //  1 KB
    int*    tope    = (int*)(ws + 35653632);            // 32 KB
    float*  topw    = (float*)(ws + 35686400);          // 32 KB

    k_prep     <<<2048, 256, 0, stream>>>(x, ctx, xs, ctxH, ctxL);
    k_split_w1t<<<dim3(16, 8), 256, 0, stream>>>(W1, w1th, w1tl);
    k_prep_wi  <<<dim3(8, 16), 256, 0, stream>>>(Wi, wiT);
    k_gemm1s   <<<dim3(16, 32), 256, 0, stream>>>(ctxH, ctxL, w1th, w1tl, b1, H);
    k_logits   <<<dim3(12, 32), 256, 0, stream>>>(H, x, W2, Wg, partial);
    k_topk     <<<512, 256, 0, stream>>>(partial, b2, bg, tope, topw);
    k_bucket   <<<64, 256, 0, stream>>>(tope, topw, counts, bslot, bw);
    k_items    <<<1, 64, 0, stream>>>(counts, sched);
    k_expert   <<<dim3(8, 192), 256, 0, stream>>>(xs, Wt, bt, ch, counts, bslot, bw, sched, scratch);
    k_combine  <<<512, 256, 0, stream>>>(scratch, xs);
    k_integrate<<<dim3(8, 32), 256, 0, stream>>>(xs, wiT, bi, out);
}

// Round 16
// 96.567 us; speedup vs baseline: 1.0552x; 1.0552x over previous
//
#include <hip/hip_runtime.h>
#include <hip/hip_bf16.h>

#define T_TOK 2048
#define D_    512
#define TWO_D 1024
#define M_    64

typedef float  f32x4  __attribute__((ext_vector_type(4)));
typedef __bf16 bf16x8 __attribute__((ext_vector_type(8)));
typedef unsigned short ushort8v __attribute__((ext_vector_type(8)));

__device__ __forceinline__ ushort f2bf(float f) {
    union { __hip_bfloat16 h; ushort u; } cv;
    cv.h = __float2bfloat16(f);
    return cv.u;
}
__device__ __forceinline__ float bf2f(ushort u) {
    union { unsigned int i; float f; } c; c.i = ((unsigned int)u) << 16; return c.f;
}

// async global->LDS, 16 bytes per lane (dest linear: uniform base + lane*16)
__device__ __forceinline__ void gl16(const void* g, void* l) {
    __builtin_amdgcn_global_load_lds(
        (const __attribute__((address_space(1))) unsigned int*)g,
        (__attribute__((address_space(3))) unsigned int*)l, 16, 0, 0);
}

// ---------------- fused prep: x-cast | ctx-split | W1T-split | WiT-cast ------
// grid 2304: [0,1024) x-cast, [1024,2048) ctx-split, [2048,2176) W1T, [2176,2304) WiT
__global__ __launch_bounds__(256) void k_prep_all(const float* __restrict__ x,
                                                  const float* __restrict__ ctx,
                                                  const float* __restrict__ W1,
                                                  const float* __restrict__ Wi,
                                                  ushort* __restrict__ xs,
                                                  ushort* __restrict__ cH,
                                                  ushort* __restrict__ cL,
                                                  ushort* __restrict__ w1th,
                                                  ushort* __restrict__ w1tl,
                                                  ushort* __restrict__ wiT) {
    int b = blockIdx.x;
    int t = threadIdx.x;
    if (b < 1024) {
        int idx = b * 256 + t;
        int e4  = idx * 4;
        int tok = e4 >> 9;
        int d   = e4 & 511;
        float4 v = *reinterpret_cast<const float4*>(x + e4);
        ushort4 o;
        o.x = f2bf(v.x); o.y = f2bf(v.y); o.z = f2bf(v.z); o.w = f2bf(v.w);
        *reinterpret_cast<ushort4*>(xs + (size_t)tok * TWO_D + d) = o;
    } else if (b < 2048) {
        int idx = (b - 1024) * 256 + t;
        float4 v = *reinterpret_cast<const float4*>(ctx + (size_t)idx * 4);
        ushort4 h, l;
        h.x = f2bf(v.x); l.x = f2bf(v.x - bf2f(h.x));
        h.y = f2bf(v.y); l.y = f2bf(v.y - bf2f(h.y));
        h.z = f2bf(v.z); l.z = f2bf(v.z - bf2f(h.z));
        h.w = f2bf(v.w); l.w = f2bf(v.w - bf2f(h.w));
        *reinterpret_cast<ushort4*>(cH + (size_t)idx * 4) = h;
        *reinterpret_cast<ushort4*>(cL + (size_t)idx * 4) = l;
    } else if (b < 2176) {
        int bb = b - 2048;                       // dim (16,8): bx=n-tile, by=k-tile
        int n  = (bb & 15) * 64 + (t >> 2);
        int kb = (bb >> 4) * 64 + (t & 3) * 16;
#pragma unroll
        for (int j = 0; j < 16; j += 4) {
            ushort hh[4], ll[4];
#pragma unroll
            for (int i = 0; i < 4; i++) {
                float v = W1[(size_t)(kb + j + i) * TWO_D + n];
                ushort h = f2bf(v);
                hh[i] = h;
                ll[i] = f2bf(v - bf2f(h));
            }
            ushort4 h4, l4;
            h4.x = hh[0]; h4.y = hh[1]; h4.z = hh[2]; h4.w = hh[3];
            l4.x = ll[0]; l4.y = ll[1]; l4.z = ll[2]; l4.w = ll[3];
            *reinterpret_cast<ushort4*>(&w1th[(size_t)n * D_ + kb + j]) = h4;
            *reinterpret_cast<ushort4*>(&w1tl[(size_t)n * D_ + kb + j]) = l4;
        }
    } else {
        int bb = b - 2176;                       // dim (8,16): bx=n-tile, by=k-tile
        int n  = (bb & 7) * 64 + (t >> 2);
        int kb = (bb >> 3) * 64 + (t & 3) * 16;
#pragma unroll
        for (int j = 0; j < 16; j += 4) {
            ushort hh[4];
#pragma unroll
            for (int i = 0; i < 4; i++)
                hh[i] = f2bf(Wi[(size_t)(kb + j + i) * D_ + n]);
            ushort4 h4;
            h4.x = hh[0]; h4.y = hh[1]; h4.z = hh[2]; h4.w = hh[3];
            *reinterpret_cast<ushort4*>(&wiT[(size_t)n * TWO_D + kb + j]) = h4;
        }
    }
}

// ---------------- selector GEMM1 via split-bf16 MFMA, BK=64 ------------------
__global__ __launch_bounds__(256) void k_gemm1s(const ushort* __restrict__ cH,
                                                const ushort* __restrict__ cL,
                                                const ushort* __restrict__ w1th,
                                                const ushort* __restrict__ w1tl,
                                                const float* __restrict__ b1,
                                                float* __restrict__ H) {
    int col0 = blockIdx.x * 64, r0 = blockIdx.y * 64;
    __shared__ ushort sAH[2 * 4096], sAL[2 * 4096];
    __shared__ ushort sBH[2 * 4096], sBL[2 * 4096];
    int t = threadIdx.x, lane = t & 63, wave = t >> 6;
    int wm = wave >> 1, wn = wave & 1;
    int lr = lane & 15, kq = lane >> 4;

    const ushort* srcAH = cH  + (size_t)(r0  + (t >> 3)) * D_ + (t & 7) * 8;
    const ushort* srcAL = cL  + (size_t)(r0  + (t >> 3)) * D_ + (t & 7) * 8;
    const ushort* srcBH = w1th + (size_t)(col0 + (t >> 3)) * D_ + (t & 7) * 8;
    const ushort* srcBL = w1tl + (size_t)(col0 + (t >> 3)) * D_ + (t & 7) * 8;
    int r2 = (256 + t) >> 3, p2 = ((256 + t) & 7) * 8;
    const ushort* srcAH2 = cH  + (size_t)(r0  + r2) * D_ + p2;
    const ushort* srcAL2 = cL  + (size_t)(r0  + r2) * D_ + p2;
    const ushort* srcBH2 = w1th + (size_t)(col0 + r2) * D_ + p2;
    const ushort* srcBL2 = w1tl + (size_t)(col0 + r2) * D_ + p2;

    f32x4 acc[2][2];
#pragma unroll
    for (int i = 0; i < 2; i++)
#pragma unroll
        for (int j = 0; j < 2; j++)
#pragma unroll
            for (int r = 0; r < 4; r++) acc[i][j][r] = 0.0f;

    gl16(srcAH, &sAH[0] + t * 8);  gl16(srcAH2, &sAH[0] + 2048 + t * 8);
    gl16(srcAL, &sAL[0] + t * 8);  gl16(srcAL2, &sAL[0] + 2048 + t * 8);
    gl16(srcBH, &sBH[0] + t * 8);  gl16(srcBH2, &sBH[0] + 2048 + t * 8);
    gl16(srcBL, &sBL[0] + t * 8);  gl16(srcBL2, &sBL[0] + 2048 + t * 8);
    __syncthreads();

    int cur = 0;
    for (int k0 = 0; k0 < D_; k0 += 64) {
        int nxt = cur ^ 1;
        if (k0 + 64 < D_) {
            int kn = k0 + 64;
            gl16(srcAH + kn, &sAH[nxt * 4096] + t * 8);  gl16(srcAH2 + kn, &sAH[nxt * 4096] + 2048 + t * 8);
            gl16(srcAL + kn, &sAL[nxt * 4096] + t * 8);  gl16(srcAL2 + kn, &sAL[nxt * 4096] + 2048 + t * 8);
            gl16(srcBH + kn, &sBH[nxt * 4096] + t * 8);  gl16(srcBH2 + kn, &sBH[nxt * 4096] + 2048 + t * 8);
            gl16(srcBL + kn, &sBL[nxt * 4096] + t * 8);  gl16(srcBL2 + kn, &sBL[nxt * 4096] + 2048 + t * 8);
        }
#pragma unroll
        for (int kc = 0; kc < 2; kc++) {
            bf16x8 ah[2], al[2], bh[2], bl[2];
#pragma unroll
            for (int i = 0; i < 2; i++) {
                int off = cur * 4096 + (wm * 32 + i * 16 + lr) * 64 + kc * 32 + kq * 8;
                ah[i] = *reinterpret_cast<const bf16x8*>(&sAH[off]);
                al[i] = *reinterpret_cast<const bf16x8*>(&sAL[off]);
            }
#pragma unroll
            for (int j = 0; j < 2; j++) {
                int off = cur * 4096 + (wn * 32 + j * 16 + lr) * 64 + kc * 32 + kq * 8;
                bh[j] = *reinterpret_cast<const bf16x8*>(&sBH[off]);
                bl[j] = *reinterpret_cast<const bf16x8*>(&sBL[off]);
            }
#pragma unroll
            for (int i = 0; i < 2; i++)
#pragma unroll
                for (int j = 0; j < 2; j++) {
                    acc[i][j] = __builtin_amdgcn_mfma_f32_16x16x32_bf16(ah[i], bh[j], acc[i][j], 0, 0, 0);
                    acc[i][j] = __builtin_amdgcn_mfma_f32_16x16x32_bf16(ah[i], bl[j], acc[i][j], 0, 0, 0);
                    acc[i][j] = __builtin_amdgcn_mfma_f32_16x16x32_bf16(al[i], bh[j], acc[i][j], 0, 0, 0);
                }
        }
        __syncthreads();
        cur = nxt;
    }

#pragma unroll
    for (int i = 0; i < 2; i++)
#pragma unroll
        for (int j = 0; j < 2; j++) {
            int col = col0 + wn * 32 + j * 16 + lr;
            float bb = b1[col];
#pragma unroll
            for (int r = 0; r < 4; r++) {
                int row = r0 + wm * 32 + i * 16 + kq * 4 + r;
                float v = acc[i][j][r] + bb;
                H[(size_t)row * TWO_D + col] = 0.5f * v * (1.0f + erff(v * 0.70710678118654752f));
            }
        }
}

// ---------------- logits partials: fp32 GEMM, K split across blocks ----------
__global__ __launch_bounds__(256) void k_logits(const float* __restrict__ H,
                                                const float* __restrict__ x,
                                                const float* __restrict__ W2,
                                                const float* __restrict__ Wg,
                                                float* __restrict__ partial) {
    __shared__ float sa[64][36];
    __shared__ float sb[32][64];
    int tx = threadIdx.x & 15, ty = threadIdx.x >> 4;
    int cx = blockIdx.x;
    int row0 = blockIdx.y * 64;

    const float* Asrc; int lda, koff;
    if (cx < 8) { Asrc = H; lda = TWO_D; koff = cx * 128; }
    else        { Asrc = x; lda = D_;    koff = (cx - 8) * 128; }

    float acc[4][4];
#pragma unroll
    for (int i = 0; i < 4; i++)
#pragma unroll
        for (int j = 0; j < 4; j++) acc[i][j] = 0.0f;

    for (int k0 = 0; k0 < 128; k0 += 32) {
#pragma unroll
        for (int q = 0; q < 2; q++) {
            int f = threadIdx.x * 2 + q;
            int r = f >> 3, c = (f & 7) * 4;
            *reinterpret_cast<float4*>(&sa[r][c]) =
                *reinterpret_cast<const float4*>(&Asrc[(size_t)(row0 + r) * lda + koff + k0 + c]);
            if (cx < 8) {
                int kk = f >> 4, n4 = (f & 15) * 4;
                *reinterpret_cast<float4*>(&sb[kk][n4]) =
                    *reinterpret_cast<const float4*>(&W2[(size_t)(koff + k0 + kk) * M_ + n4]);
            } else {
                int m = f >> 3, kq = f & 7;
                float4 v2 = *reinterpret_cast<const float4*>(&Wg[(size_t)m * D_ + koff + k0 + kq * 4]);
                sb[kq * 4 + 0][m] = v2.x; sb[kq * 4 + 1][m] = v2.y;
                sb[kq * 4 + 2][m] = v2.z; sb[kq * 4 + 3][m] = v2.w;
            }
        }
        __syncthreads();
#pragma unroll
        for (int kk = 0; kk < 32; kk++) {
            float a0 = sa[ty * 4 + 0][kk], a1 = sa[ty * 4 + 1][kk];
            float a2 = sa[ty * 4 + 2][kk], a3 = sa[ty * 4 + 3][kk];
            float4 b4 = *reinterpret_cast<float4*>(&sb[kk][tx * 4]);
            acc[0][0] += a0 * b4.x; acc[0][1] += a0 * b4.y; acc[0][2] += a0 * b4.z; acc[0][3] += a0 * b4.w;
            acc[1][0] += a1 * b4.x; acc[1][1] += a1 * b4.y; acc[1][2] += a1 * b4.z; acc[1][3] += a1 * b4.w;
            acc[2][0] += a2 * b4.x; acc[2][1] += a2 * b4.y; acc[2][2] += a2 * b4.z; acc[2][3] += a2 * b4.w;
            acc[3][0] += a3 * b4.x; acc[3][1] += a3 * b4.y; acc[3][2] += a3 * b4.z; acc[3][3] += a3 * b4.w;
        }
        __syncthreads();
    }
#pragma unroll
    for (int i = 0; i < 4; i++) {
        int row = row0 + ty * 4 + i;
        float4 o;
        float* oc = reinterpret_cast<float*>(&o);
#pragma unroll
        for (int j = 0; j < 4; j++) oc[j] = acc[i][j];
        *reinterpret_cast<float4*>(&partial[((size_t)cx * T_TOK + row) * M_ + tx * 4]) = o;
    }
}

// ---------------- top-k: one token per wave; no atomics ----------------------
__global__ __launch_bounds__(256) void k_topk(const float* __restrict__ partial,
                                              const float* __restrict__ b2,
                                              const float* __restrict__ bg,
                                              int* __restrict__ tope,
                                              float* __restrict__ topw) {
    int t = threadIdx.x;
    int wave = t >> 6, lane = t & 63;
    int tok = blockIdx.x * 4 + wave;

    float l = b2[lane];
#pragma unroll
    for (int c = 0; c < 8; c++)
        l += partial[((size_t)c * T_TOK + tok) * M_ + lane];
    float g = bg[lane];
#pragma unroll
    for (int c = 8; c < 12; c++)
        g += partial[((size_t)c * T_TOK + tok) * M_ + lane];

    float mx = l;
#pragma unroll
    for (int off = 1; off < 64; off <<= 1) mx = fmaxf(mx, __shfl_xor(mx, off));
    float ev = expf(l - mx);
    float s = ev;
#pragma unroll
    for (int off = 1; off < 64; off <<= 1) s += __shfl_xor(s, off);
    float p = ev / s;

    float pm = p;
    int bi0, bi1, bi2, bi3; float bv0, bv1, bv2, bv3;
#pragma unroll
    for (int k = 0; k < 4; k++) {
        float bv = pm; int bi = lane;
#pragma unroll
        for (int off = 1; off < 64; off <<= 1) {
            float ov = __shfl_xor(bv, off);
            int   oi = __shfl_xor(bi, off);
            if (ov > bv || (ov == bv && oi < bi)) { bv = ov; bi = oi; }
        }
        if (k == 0) { bi0 = bi; bv0 = bv; }
        else if (k == 1) { bi1 = bi; bv1 = bv; }
        else if (k == 2) { bi2 = bi; bv2 = bv; }
        else { bi3 = bi; bv3 = bv; }
        if (lane == bi) pm = -1.0f;
    }
    float sum4 = bv0 + bv1 + bv2 + bv3;
    int   esel = (lane == 0) ? bi0 : (lane == 1) ? bi1 : (lane == 2) ? bi2 : bi3;
    float pv   = (lane == 0) ? bv0 : (lane == 1) ? bv1 : (lane == 2) ? bv2 : bv3;
    float gv = __shfl(g, esel);
    if (lane < 4) {
        float gate = 1.0f / (1.0f + expf(-gv));
        tope[tok * 4 + lane] = esel;
        topw[tok * 4 + lane] = (pv / sum4) * gate;
    }
}

// ---------------- bucket build: 1 block/expert, 4 waves, int4 scan ----------
__global__ __launch_bounds__(256) void k_bucket(const int* __restrict__ tope,
                                                const float* __restrict__ topw,
                                                int* __restrict__ counts,
                                                int* __restrict__ bslot,
                                                float* __restrict__ bw) {
    int e = blockIdx.x;
    int t = threadIdx.x, lane = t & 63, wave = t >> 6;
    __shared__ int s_wsum[4];
    __shared__ int s_base;
    if (t == 0) s_base = 0;

    for (int it = 0; it < 8; it++) {
        int base = it * 1024 + t * 4;
        int4 ev = *reinterpret_cast<const int4*>(tope + base);
        bool m0 = (ev.x == e), m1 = (ev.y == e), m2 = (ev.z == e), m3 = (ev.w == e);
        unsigned long long b0 = __ballot(m0), b1 = __ballot(m1);
        unsigned long long b2 = __ballot(m2), b3 = __ballot(m3);
        unsigned long long below = (lane == 0) ? 0ULL : ((~0ULL) >> (64 - lane));
        int pre_lane = __popcll(b0 & below) + __popcll(b1 & below)
                     + __popcll(b2 & below) + __popcll(b3 & below);
        int wtot = __popcll(b0) + __popcll(b1) + __popcll(b2) + __popcll(b3);
        if (lane == 0) s_wsum[wave] = wtot;
        __syncthreads();
        int wbase = s_base;
#pragma unroll
        for (int w = 0; w < 4; w++)
            if (w < wave) wbase += s_wsum[w];
        int pos = wbase + pre_lane;
        if (m0) { bslot[e * T_TOK + pos] = base + 0; bw[e * T_TOK + pos] = topw[base + 0]; pos++; }
        if (m1) { bslot[e * T_TOK + pos] = base + 1; bw[e * T_TOK + pos] = topw[base + 1]; pos++; }
        if (m2) { bslot[e * T_TOK + pos] = base + 2; bw[e * T_TOK + pos] = topw[base + 2]; pos++; }
        if (m3) { bslot[e * T_TOK + pos] = base + 3; bw[e * T_TOK + pos] = topw[base + 3]; pos++; }
        __syncthreads();
        if (t == 0) s_base += s_wsum[0] + s_wsum[1] + s_wsum[2] + s_wsum[3];
    }
    __syncthreads();
    if (t == 0) counts[e] = s_base;
}

// ---------------- grouped expert GEMM (bf16 MFMA), BK=32, counts-derived map -
// grid (8 n-tiles, 192 items); wave 0 prefix-scans counts to find (e, y0).
__global__ __launch_bounds__(256) void k_expert(const ushort* __restrict__ xs,
                                                const float* __restrict__ Wt,
                                                const float* __restrict__ bt,
                                                const float* __restrict__ ch,
                                                const int* __restrict__ counts,
                                                const int* __restrict__ bslot,
                                                const float* __restrict__ bw,
                                                ushort* __restrict__ scratch) {
    __shared__ int s_e, s_y0, s_ni;
    int t = threadIdx.x;
    if (t < 64) {
        int cnt_t = counts[t];
        int nty = (cnt_t + 63) >> 6;
        int incl = nty;
#pragma unroll
        for (int d = 1; d < 64; d <<= 1) {
            int v = __shfl_up(incl, d);
            if (t >= d) incl += v;
        }
        int ni = __shfl(incl, 63);
        int base = incl - nty;
        int yi = blockIdx.y;
        bool mine = (yi >= base) && (yi < base + nty);
        if (mine) { s_e = t; s_y0 = (yi - base) << 6; }
        if (t == 0) s_ni = ni;
    }
    __syncthreads();
    if (blockIdx.y >= s_ni) return;
    int e  = s_e;
    int y0 = s_y0;
    int cnt = counts[e];
    int n0 = blockIdx.x * 64;

    __shared__ ushort saF[2 * 64 * 32];
    __shared__ float  sbF[2 * 32 * 64];
    __shared__ int    s_slot[64];
    __shared__ float  s_w[64];

    if (t < 64) {
        int i = y0 + t;
        if (i < cnt) { s_slot[t] = bslot[e * T_TOK + i]; s_w[t] = bw[e * T_TOK + i]; }
        else         { s_slot[t] = -1;                   s_w[t] = 0.0f; }
    }
    __syncthreads();

    int lane = t & 63, wave = t >> 6;
    int wm = wave >> 1, wn = wave & 1;
    int lr = lane & 15, kq = lane >> 4;

    int rA = t >> 2, qA = t & 3;
    int slotA = s_slot[rA];
    const ushort* srcA = xs + (size_t)((slotA >= 0) ? (slotA >> 2) : 0) * TWO_D + qA * 8;
    const float* srcB0 = &Wt[((size_t)e * D_ + (t >> 4)) * D_ + n0 + (t & 15) * 4];
    const float* srcB1 = &Wt[((size_t)e * D_ + 16 + (t >> 4)) * D_ + n0 + (t & 15) * 4];

    f32x4 acc[2][2];
#pragma unroll
    for (int i = 0; i < 2; i++)
#pragma unroll
        for (int j = 0; j < 2; j++)
#pragma unroll
            for (int r = 0; r < 4; r++) acc[i][j][r] = 0.0f;

    gl16(srcA, &saF[0] + t * 8);
    gl16(srcB0, &sbF[0] + t * 4);
    gl16(srcB1, &sbF[0] + 1024 + t * 4);
    __syncthreads();

    int cur = 0;
    for (int k0 = 0; k0 < D_; k0 += 32) {
        int nxt = cur ^ 1;
        if (k0 + 32 < D_) {
            gl16(srcA + k0 + 32, &saF[nxt * 2048] + t * 8);
            gl16(srcB0 + (size_t)(k0 + 32) * D_, &sbF[nxt * 2048] + t * 4);
            gl16(srcB1 + (size_t)(k0 + 32) * D_, &sbF[nxt * 2048] + 1024 + t * 4);
        }
        bf16x8 af[2], bfr[2];
#pragma unroll
        for (int i = 0; i < 2; i++)
            af[i] = *reinterpret_cast<const bf16x8*>(&saF[cur * 2048 + (wm * 32 + i * 16 + lr) * 32 + kq * 8]);
#pragma unroll
        for (int j = 0; j < 2; j++) {
            int col = wn * 32 + j * 16 + lr;
            union { ushort us[8]; bf16x8 v; } pk;
#pragma unroll
            for (int jj = 0; jj < 8; jj++)
                pk.us[jj] = f2bf(sbF[cur * 2048 + (kq * 8 + jj) * 64 + col]);
            bfr[j] = pk.v;
        }
#pragma unroll
        for (int i = 0; i < 2; i++)
#pragma unroll
            for (int j = 0; j < 2; j++)
                acc[i][j] = __builtin_amdgcn_mfma_f32_16x16x32_bf16(af[i], bfr[j], acc[i][j], 0, 0, 0);
        __syncthreads();
        cur = nxt;
    }

#pragma unroll
    for (int i = 0; i < 2; i++)
#pragma unroll
        for (int j = 0; j < 2; j++) {
            int col = n0 + wn * 32 + j * 16 + lr;
            float bias = bt[(size_t)e * D_ + col] + ch[(size_t)e * D_ + col];
#pragma unroll
            for (int r = 0; r < 4; r++) {
                int rl = wm * 32 + i * 16 + kq * 4 + r;
                int slot = s_slot[rl];
                if (slot >= 0)
                    scratch[(size_t)slot * D_ + col] = f2bf((acc[i][j][r] + bias) * s_w[rl]);
            }
        }
}

// ---------------- combine 4 slots -> selected (bf16) into xs[:, 512:] -------
__global__ __launch_bounds__(256) void k_combine(const ushort* __restrict__ scratch,
                                                 ushort* __restrict__ xs) {
    int tid = blockIdx.x * 256 + threadIdx.x;   // 512 blocks x 256
    int token = tid >> 6;
    int d8 = (tid & 63) * 8;
    float s[8];
#pragma unroll
    for (int j = 0; j < 8; j++) s[j] = 0.0f;
#pragma unroll
    for (int r = 0; r < 4; r++) {
        ushort8v v = *reinterpret_cast<const ushort8v*>(scratch + ((size_t)token * 4 + r) * D_ + d8);
#pragma unroll
        for (int j = 0; j < 8; j++) s[j] += bf2f(v[j]);
    }
    ushort8v o;
#pragma unroll
    for (int j = 0; j < 8; j++) o[j] = f2bf(s[j]);
    *reinterpret_cast<ushort8v*>(xs + (size_t)token * TWO_D + D_ + d8) = o;
}

// ---------------- integrate: out = [x, selected] @ wiT + int_b, BK=64 -------
__global__ __launch_bounds__(256) void k_integrate(const ushort* __restrict__ xs,
                                                   const ushort* __restrict__ wiT,
                                                   const float* __restrict__ bi,
                                                   float* __restrict__ out) {
    int n0 = blockIdx.x * 64, r0 = blockIdx.y * 64;
    __shared__ ushort saF[2 * 4096];
    __shared__ ushort sbB[2 * 4096];
    int t = threadIdx.x, lane = t & 63, wave = t >> 6;
    int wm = wave >> 1, wn = wave & 1;
    int lr = lane & 15, kq = lane >> 4;

    int rA0 = t >> 3, pA0 = (t & 7) * 8;
    int rA1 = (256 + t) >> 3, pA1 = ((256 + t) & 7) * 8;
    const ushort* srcA0 = xs + (size_t)(r0 + rA0) * TWO_D + pA0;
    const ushort* srcA1 = xs + (size_t)(r0 + rA1) * TWO_D + pA1;
    const ushort* srcB0 = wiT + (size_t)(n0 + rA0) * TWO_D + pA0;
    const ushort* srcB1 = wiT + (size_t)(n0 + rA1) * TWO_D + pA1;

    f32x4 acc[2][2];
#pragma unroll
    for (int i = 0; i < 2; i++)
#pragma unroll
        for (int j = 0; j < 2; j++)
#pragma unroll
            for (int r = 0; r < 4; r++) acc[i][j][r] = 0.0f;

    gl16(srcA0, &saF[0] + t * 8);
    gl16(srcA1, &saF[0] + 2048 + t * 8);
    gl16(srcB0, &sbB[0] + t * 8);
    gl16(srcB1, &sbB[0] + 2048 + t * 8);
    __syncthreads();

    int cur = 0;
    for (int k0 = 0; k0 < TWO_D; k0 += 64) {
        int nxt = cur ^ 1;
        if (k0 + 64 < TWO_D) {
            int kn = k0 + 64;
            gl16(srcA0 + kn, &saF[nxt * 4096] + t * 8);
            gl16(srcA1 + kn, &saF[nxt * 4096] + 2048 + t * 8);
            gl16(srcB0 + kn, &sbB[nxt * 4096] + t * 8);
            gl16(srcB1 + kn, &sbB[nxt * 4096] + 2048 + t * 8);
        }
#pragma unroll
        for (int kc = 0; kc < 2; kc++) {
            bf16x8 af[2], bfr[2];
#pragma unroll
            for (int i = 0; i < 2; i++)
                af[i] = *reinterpret_cast<const bf16x8*>(
                    &saF[cur * 4096 + (wm * 32 + i * 16 + lr) * 64 + kc * 32 + kq * 8]);
#pragma unroll
            for (int j = 0; j < 2; j++)
                bfr[j] = *reinterpret_cast<const bf16x8*>(
                    &sbB[cur * 4096 + (wn * 32 + j * 16 + lr) * 64 + kc * 32 + kq * 8]);
#pragma unroll
            for (int i = 0; i < 2; i++)
#pragma unroll
                for (int j = 0; j < 2; j++)
                    acc[i][j] = __builtin_amdgcn_mfma_f32_16x16x32_bf16(af[i], bfr[j], acc[i][j], 0, 0, 0);
        }
        __syncthreads();
        cur = nxt;
    }

#pragma unroll
    for (int i = 0; i < 2; i++)
#pragma unroll
        for (int j = 0; j < 2; j++) {
            int col = n0 + wn * 32 + j * 16 + lr;
            float bb = bi[col];
#pragma unroll
            for (int r = 0; r < 4; r++) {
                int row = r0 + wm * 32 + i * 16 + kq * 4 + r;
                out[(size_t)row * D_ + col] = acc[i][j][r] + bb;
            }
        }
}

extern "C" void kernel_launch(void* const* d_in, const int* in_sizes, int n_in,
                              void* d_out, int out_size, void* d_ws, size_t ws_size,
                              hipStream_t stream) {
    const float* x   = (const float*)d_in[0];
    const float* ctx = (const float*)d_in[1];
    const float* Wt  = (const float*)d_in[2];
    const float* bt  = (const float*)d_in[3];
    const float* ch  = (const float*)d_in[4];
    const float* Wg  = (const float*)d_in[5];
    const float* bg  = (const float*)d_in[6];
    const float* W1  = (const float*)d_in[7];
    const float* b1  = (const float*)d_in[8];
    const float* W2  = (const float*)d_in[9];
    const float* b2  = (const float*)d_in[10];
    const float* Wi  = (const float*)d_in[11];
    const float* bi  = (const float*)d_in[12];
    float* out = (float*)d_out;

    char* ws = (char*)d_ws;
    float*  H       = (float*)(ws + 0);                 //  8 MB
    ushort* xs      = (ushort*)(ws + 8388608);          //  4 MB
    int*    counts  = (int*)(ws + 12582912);            //  1 KB
    int*    bslot   = (int*)(ws + 12583936);            // 512 KB
    float*  bw      = (float*)(ws + 13108224);          // 512 KB
    ushort* scratch = (ushort*)(ws + 13632512);         //  8 MB [8192][512] bf16
    float*  partial = (float*)(ws + 22021120);          //  6 MB [12][2048][64]
    ushort* ctxH    = (ushort*)(ws + 28312576);         //  2 MB
    ushort* ctxL    = (ushort*)(ws + 30409728);         //  2 MB
    ushort* w1th    = (ushort*)(ws + 32506880);         //  1 MB
    ushort* w1tl    = (ushort*)(ws + 33555456);         //  1 MB
    ushort* wiT     = (ushort*)(ws + 34604032);         //  1 MB [512][1024] bf16
    int*    tope    = (int*)(ws + 35653632);            // 32 KB
    float*  topw    = (float*)(ws + 35686400);          // 32 KB

    k_prep_all <<<2304, 256, 0, stream>>>(x, ctx, W1, Wi, xs, ctxH, ctxL, w1th, w1tl, wiT);
    k_gemm1s   <<<dim3(16, 32), 256, 0, stream>>>(ctxH, ctxL, w1th, w1tl, b1, H);
    k_logits   <<<dim3(12, 32), 256, 0, stream>>>(H, x, W2, Wg, partial);
    k_topk     <<<512, 256, 0, stream>>>(partial, b2, bg, tope, topw);
    k_bucket   <<<64, 256, 0, stream>>>(tope, topw, counts, bslot, bw);
    k_expert   <<<dim3(8, 192), 256, 0, stream>>>(xs, Wt, bt, ch, counts, bslot, bw, scratch);
    k_combine  <<<512, 256, 0, stream>>>(scratch, xs);
    k_integrate<<<dim3(8, 32), 256, 0, stream>>>(xs, wiT, bi, out);
}